// Round 1
// 147.123 us; speedup vs baseline: 1.0308x; 1.0308x over previous
//
#include <hip/hip_runtime.h>

#define T_SEQ 2048
#define DHEAD 128
#define NBH 16
#define SCALE 0.08838834764831845f

typedef unsigned short u16;
typedef unsigned int u32;
typedef u16 u16x4 __attribute__((ext_vector_type(4)));
typedef u16 u16x8 __attribute__((ext_vector_type(8)));
typedef u32 u32x2 __attribute__((ext_vector_type(2)));
typedef short s16x4 __attribute__((ext_vector_type(4)));
typedef __bf16 bf16x8 __attribute__((ext_vector_type(8)));
typedef float f32x4 __attribute__((ext_vector_type(4)));

__device__ __forceinline__ u16 f2bfu(float x) {
  union { float f; unsigned u; } c; c.f = x;
  unsigned u = c.u;
  u = u + 0x7FFFu + ((u >> 16) & 1u);   // RNE
  return (u16)(u >> 16);
}

__device__ __forceinline__ u32 packbf2(float lo, float hi) {
  return (u32)f2bfu(lo) | ((u32)f2bfu(hi) << 16);
}

__device__ __forceinline__ bf16x8 ldsFrag(const u16* p) {
  u16x8 t = *(const u16x8*)p;
  return __builtin_bit_cast(bf16x8, t);
}

__device__ __forceinline__ f32x4 mfma16x16x16bf16(s16x4 a, s16x4 b, f32x4 c) {
#if __has_builtin(__builtin_amdgcn_mfma_f32_16x16x16bf16_1k)
  return __builtin_amdgcn_mfma_f32_16x16x16bf16_1k(a, b, c, 0, 0, 0);
#else
  asm("v_mfma_f32_16x16x16_bf16 %0, %1, %2, %0" : "+v"(c) : "v"(a), "v"(b));
  return c;
#endif
}

__device__ __forceinline__ void gld_lds16(const void* g, void* l) {
  __builtin_amdgcn_global_load_lds(
      (__attribute__((address_space(1))) const unsigned int*)g,
      (__attribute__((address_space(3))) unsigned int*)l, 16, 0, 0);
}

// ---------------------------------------------------------------------------
// Gate scan: fc=cumsum(logsigmoid(f)); a=i-fc; c=cummax(a).
// 1024 thr x 2 elems; shfl wave-scans + tiny cross-wave scan (4 barriers).
// ---------------------------------------------------------------------------
__global__ __launch_bounds__(1024) void gate_scan_kernel(
    const float* __restrict__ ig, const float* __restrict__ fg,
    float* __restrict__ a_out, float* __restrict__ c_out,
    float* __restrict__ fc_out)
{
  const int bh = blockIdx.x, tid = threadIdx.x;
  const int w = tid >> 6, lane = tid & 63;
  const int base = bh * T_SEQ + tid * 2;
  __shared__ float wsum[16];
  __shared__ float wmax[16];

  const float x0 = fg[base], x1 = fg[base + 1];
  const float ls0 = fminf(x0, 0.f) - log1pf(expf(-fabsf(x0)));
  const float ls1 = fminf(x1, 0.f) - log1pf(expf(-fabsf(x1)));
  const float s = ls0 + ls1;

  float sc = s;
#pragma unroll
  for (int off = 1; off < 64; off <<= 1) {
    const float t = __shfl_up(sc, off, 64);
    if (lane >= off) sc += t;
  }
  if (lane == 63) wsum[w] = sc;
  __syncthreads();
  float wo = 0.f;
#pragma unroll
  for (int i = 0; i < 15; ++i) if (i < w) wo += wsum[i];
  const float excl = wo + (sc - s);
  const float fc0 = excl + ls0;
  const float fc1 = excl + ls0 + ls1;
  fc_out[base] = fc0; fc_out[base + 1] = fc1;
  const float a0 = ig[base] - fc0;
  const float a1 = ig[base + 1] - fc1;
  a_out[base] = a0; a_out[base + 1] = a1;

  const float m = fmaxf(a0, a1);
  float mc = m;
#pragma unroll
  for (int off = 1; off < 64; off <<= 1) {
    const float t = __shfl_up(mc, off, 64);
    if (lane >= off) mc = fmaxf(mc, t);
  }
  if (lane == 63) wmax[w] = mc;
  __syncthreads();
  float wmo = -INFINITY;
#pragma unroll
  for (int i = 0; i < 15; ++i) if (i < w) wmo = fmaxf(wmo, wmax[i]);
  const float prev = __shfl_up(mc, 1, 64);
  float exclm = (lane > 0) ? prev : -INFINITY;
  exclm = fmaxf(exclm, wmo);
  c_out[base] = fmaxf(exclm, a0);
  c_out[base + 1] = fmaxf(exclm, m);
}

// ---------------------------------------------------------------------------
// Pre-pass: K_hat = K * exp(a[s] - c_tile_end(s)), fp32 -> bf16.
// ---------------------------------------------------------------------------
__global__ __launch_bounds__(256) void cvt_k_kernel(
    const float* __restrict__ src, const float* __restrict__ ag,
    const float* __restrict__ cg, u16* __restrict__ dst)
{
  const int i = (blockIdx.x * 256 + threadIdx.x) * 4;
  const int bhs = i >> 7;
  const float sc = __expf(ag[bhs] - cg[bhs | 63]);  // <= 1
  const float4 x = *(const float4*)(src + i);
  u16x4 p;
  p[0] = f2bfu(x.x * sc); p[1] = f2bfu(x.y * sc);
  p[2] = f2bfu(x.z * sc); p[3] = f2bfu(x.w * sc);
  *(u16x4*)(dst + i) = p;
}

// ---------------------------------------------------------------------------
// Pre-pass: V fp32 [bh][key][n] -> bf16 transposed Vt [bh][n][key].
// ---------------------------------------------------------------------------
__global__ __launch_bounds__(256) void cvt_vt_kernel(
    const float* __restrict__ v, u16* __restrict__ vt)
{
  const int bh = blockIdx.y, kt = blockIdx.x, tid = threadIdx.x;
  __shared__ __align__(16) u16 L[128 * 72];
  const int n0 = (tid & 31) * 4, k0 = (tid >> 5) * 8;
  const float* vp = v + ((size_t)bh * T_SEQ + kt * 64 + k0) * DHEAD + n0;
  u16 tv[4][8];
#pragma unroll
  for (int rr = 0; rr < 8; ++rr) {
    const float4 x = *(const float4*)(vp + rr * DHEAD);
    tv[0][rr] = f2bfu(x.x); tv[1][rr] = f2bfu(x.y);
    tv[2][rr] = f2bfu(x.z); tv[3][rr] = f2bfu(x.w);
  }
#pragma unroll
  for (int j = 0; j < 4; ++j) {
    u16x8 p;
#pragma unroll
    for (int rr = 0; rr < 8; ++rr) p[rr] = tv[j][rr];
    *(u16x8*)(&L[(n0 + j) * 72 + k0]) = p;
  }
  __syncthreads();
  const int row = tid >> 1, s0 = (tid & 1) * 32;
  u16* op = vt + ((size_t)bh * DHEAD + row) * T_SEQ + kt * 64 + s0;
#pragma unroll
  for (int i = 0; i < 4; ++i)
    *(u16x8*)(op + i * 8) = *(const u16x8*)(&L[row * 72 + s0 + i * 8]);
}

// ---------------------------------------------------------------------------
// Main flash mLSTM.  256 blocks x 1024 thr (16 waves = 4/SIMD).
// UNIFORM schedule: block (bh,p) runs tile A=31-p (stages 0..31-p) then
// tile B=p (stages 0..p) sequentially with ALL 16 waves: exactly 33
// compute-iterations for EVERY block (no idle waves, no tail imbalance).
// Wave = key-group kg(4) x row-quarter rq(4): 16 keys x 16 qrows each.
//   S^T = K_hat Q^T (16x16x32): A=K from LDS, B=Q in regs; P in registers.
//   O^T += V^T P^T (16x16x16), partial over 16 keys, combined in epilogue.
// dbuf async staging, 1 barrier/iter; B-phase stage-0 prefetched during the
// last A iteration; per-phase epilogue (33 KB osh, disjoint from staging).
// ---------------------------------------------------------------------------
template <bool FAST>
__global__ __launch_bounds__(1024, 4) void mlstm_fwd_kernel(
    const float* __restrict__ qg, const float* __restrict__ kxg,
    const float* __restrict__ vg,
    const u16* __restrict__ kbf, const u16* __restrict__ vtbf,
    const float* __restrict__ ag, const float* __restrict__ cg,
    const float* __restrict__ fcg, float* __restrict__ out)
{
  const int bx = (int)blockIdx.x;
  const int bh = bx & 15, p = bx >> 4;
  const int tid = (int)threadIdx.x;
  const int w = tid >> 6, lane = tid & 63;
  const int quad = lane >> 4, l16 = lane & 15;
  const int kg = w & 3, rq = w >> 2;

  const int qtA = 31 - p, qtB = p;
  const int nA = qtA + 1;                 // 32-p; nA + (qtB+1) == 33 for all p

  // LDS: K dbuf 2x16K @0, V dbuf 2x16K @32768 (loop);
  //      osh 64x129 f32 @65536 (33024 B), rsh 4x64 f32 @98560.
  __shared__ __align__(16) unsigned char SM[99584];
  u16* Kst = (u16*)SM;
  u16* Vst = (u16*)(SM + 32768);
  float* osh = (float*)(SM + 65536);
  float* rsh = (float*)(SM + 98560);

  const size_t hoff = (size_t)bh * T_SEQ * DHEAD;
  const int goff = bh * T_SEQ;

  // Q -> B-frags qf[kc]: B[k=quad*8+j][n=l16], row = qt*64 + rq*16 + l16
  bf16x8 qf[4];
  auto loadQ = [&](int lqt) {
    const float* qp = qg + hoff + (size_t)(lqt * 64 + rq * 16 + l16) * DHEAD + quad * 8;
#pragma unroll
    for (int kc = 0; kc < 4; ++kc) {
      const float4 x0 = *(const float4*)(qp + kc * 32);
      const float4 x1 = *(const float4*)(qp + kc * 32 + 4);
      u16x8 t;
      t[0] = f2bfu(x0.x); t[1] = f2bfu(x0.y); t[2] = f2bfu(x0.z); t[3] = f2bfu(x0.w);
      t[4] = f2bfu(x1.x); t[5] = f2bfu(x1.y); t[6] = f2bfu(x1.z); t[7] = f2bfu(x1.w);
      qf[kc] = __builtin_bit_cast(bf16x8, t);
    }
  };

  f32x4 oa[8];                           // O^T partial: 8 vd-tiles (16 qrows)
  float rsacc;
  auto zeroAcc = [&]() {
#pragma unroll
    for (int mt = 0; mt < 8; ++mt) oa[mt] = (f32x4){0.f, 0.f, 0.f, 0.f};
    rsacc = 0.f;
  };
  zeroAcc();

  auto stage = [&](int st, int b) {
    u16* KbL = Kst + b * 8192;
    u16* VbL = Vst + b * 8192;
    if (FAST) {
      const u16* ks = kbf + ((size_t)goff + st * 64) * DHEAD;
      const u16* vs = vtbf + (size_t)bh * DHEAD * T_SEQ + st * 64;
      { const int key = tid >> 4; const int db = (tid & 15) ^ (key & 7);
        gld_lds16(ks + (size_t)key * DHEAD + db * 8, KbL + w * 512); }
      { const int n = tid >> 3; const int kb = (tid & 7) ^ (n & 7);
        gld_lds16(vs + (size_t)n * T_SEQ + kb * 8, VbL + w * 512); }
    } else {
      const float ct = cg[goff + st * 64 + 63];
      const float* kp = kxg + hoff + (size_t)(st * 64) * DHEAD;
      const float* vp = vg + hoff + (size_t)(st * 64) * DHEAD;
      { const int key = tid >> 4; const int db = (tid & 15) ^ (key & 7);
        const float sc = __expf(ag[goff + st * 64 + key] - ct);
        const float4 x0 = *(const float4*)(kp + (size_t)key * DHEAD + db * 8);
        const float4 x1 = *(const float4*)(kp + (size_t)key * DHEAD + db * 8 + 4);
        u16x8 pk;
        pk[0] = f2bfu(x0.x * sc); pk[1] = f2bfu(x0.y * sc);
        pk[2] = f2bfu(x0.z * sc); pk[3] = f2bfu(x0.w * sc);
        pk[4] = f2bfu(x1.x * sc); pk[5] = f2bfu(x1.y * sc);
        pk[6] = f2bfu(x1.z * sc); pk[7] = f2bfu(x1.w * sc);
        *(u16x8*)(KbL + tid * 8) = pk; }
      { const int n = tid >> 3; const int kb = (tid & 7) ^ (n & 7);
        u16x8 pw;
#pragma unroll
        for (int rr = 0; rr < 8; ++rr)
          pw[rr] = f2bfu(vp[(size_t)(kb * 8 + rr) * DHEAD + n]);
        *(u16x8*)(VbL + tid * 8) = pw; }
    }
  };

  const int keyA = kg * 16 + l16;         // A-frag key row (QK)
  const int ksw  = l16 & 7;
  const int kbu  = kg * 2 + (quad >> 1);  // V unit base (PV)
  const int kofs = (quad & 1) * 4;

  auto computeTile = [&](int cqt, int st, int b, float ccmax) {
    const u16* KbL = Kst + b * 8192;
    const u16* VbL = Vst + b * 8192;

    // ---- S^T = K_hat Q^T ----
    f32x4 sa = (f32x4){0.f, 0.f, 0.f, 0.f};
#pragma unroll
    for (int kc = 0; kc < 4; ++kc) {
      const bf16x8 kf = ldsFrag(KbL + keyA * 128 + (((kc * 4 + quad) ^ ksw) * 8));
      sa = __builtin_amdgcn_mfma_f32_16x16x32_bf16(kf, qf[kc], sa, 0, 0, 0);
    }

    const float etile = SCALE * __expf(cg[goff + st * 64 + 63] - ccmax);
    float x0 = sa[0] * etile, x1 = sa[1] * etile;
    float x2 = sa[2] * etile, x3 = sa[3] * etile;
    if (st == cqt) {
      const int qr = rq * 16 + l16, kb0 = kg * 16 + quad * 4;
      if (kb0 + 0 > qr) x0 = 0.f;
      if (kb0 + 1 > qr) x1 = 0.f;
      if (kb0 + 2 > qr) x2 = 0.f;
      if (kb0 + 3 > qr) x3 = 0.f;
    }
    rsacc += (x0 + x1) + (x2 + x3);
    const s16x4 pfr = __builtin_bit_cast(s16x4, (u32x2){packbf2(x0, x1), packbf2(x2, x3)});

    // ---- O^T += V^T P^T ----
#pragma unroll
    for (int mt = 0; mt < 8; ++mt) {
      const int vd = mt * 16 + l16;
      const s16x4 va = *(const s16x4*)(VbL + vd * 64 + ((kbu ^ (vd & 7)) * 8) + kofs);
      oa[mt] = mfma16x16x16bf16(va, pfr, oa[mt]);
    }
  };

  auto epilogue = [&](int eqt, float ecmax) {
    // rowsum reduce across quads, then across key-groups via LDS
    float x = rsacc;
    x += __shfl_xor(x, 16, 64);
    x += __shfl_xor(x, 32, 64);
    if (lane < 16) rsh[kg * 64 + rq * 16 + lane] = x;
    __syncthreads();
    float inv = 0.f;
    if (kg == 3) {
      const int row = rq * 16 + l16;
      const float tot = rsh[row] + rsh[64 + row] + rsh[128 + row] + rsh[192 + row];
      const float nf = __expf(-(ecmax + fcg[goff + eqt * 64 + row]));
      inv = 1.f / fmaxf(fabsf(tot), nf);
    }
    // 4-round partial-O combine
    for (int r = 0; r < 4; ++r) {
      if (kg == r) {
#pragma unroll
        for (int mt = 0; mt < 8; ++mt)
#pragma unroll
          for (int rg = 0; rg < 4; ++rg) {
            const int row = rq * 16 + l16;
            const int vd = mt * 16 + quad * 4 + rg;
            const int ad = row * 129 + vd;
            float v = oa[mt][rg];
            if (r > 0) v += osh[ad];
            if (r == 3) v *= inv;
            osh[ad] = v;
          }
      }
      __syncthreads();
    }
    // cooperative coalesced store
    const int col = tid & 31, r0 = tid >> 5;
#pragma unroll
    for (int i = 0; i < 2; ++i) {
      const int row = r0 + 32 * i;
      const float* lp = osh + row * 129 + col * 4;
      float4 v; v.x = lp[0]; v.y = lp[1]; v.z = lp[2]; v.w = lp[3];
      *(float4*)(out + hoff + (size_t)(eqt * 64 + row) * DHEAD + col * 4) = v;
    }
  };

  // -------- phase A then phase B: 33 uniform iterations --------
  int qt = qtA;
  float cmax = cg[goff + qtA * 64 + 63];
  loadQ(qtA);
  stage(0, 0);
  __syncthreads();

  for (int it = 0; it < 33; ++it) {
    if (it < 32) {
      const int nx = it + 1;
      stage((nx < nA) ? nx : nx - nA, nx & 1);
    }
    computeTile(qt, (it < nA) ? it : it - nA, it & 1, cmax);
    __syncthreads();
    if (it == nA - 1) {
      epilogue(qtA, cmax);          // internal barriers; osh disjoint from staging
      zeroAcc();
      qt = qtB;
      cmax = cg[goff + qtB * 64 + 63];
      loadQ(qtB);
    }
  }
  epilogue(qtB, cmax);
}

// ---------------------------------------------------------------------------
extern "C" void kernel_launch(void* const* d_in, const int* in_sizes, int n_in,
                              void* d_out, int out_size, void* d_ws, size_t ws_size,
                              hipStream_t stream) {
  const float* q  = (const float*)d_in[0];
  const float* k  = (const float*)d_in[1];
  const float* v  = (const float*)d_in[2];
  const float* ig = (const float*)d_in[3];
  const float* fg = (const float*)d_in[4];

  const size_t gate_bytes = (size_t)3 * NBH * T_SEQ * sizeof(float);
  const size_t kv_elems   = (size_t)NBH * T_SEQ * DHEAD;
  const bool fast = ws_size >= gate_bytes + 2 * kv_elems * sizeof(u16);

  float* a_ws  = (float*)d_ws;
  float* c_ws  = a_ws + NBH * T_SEQ;
  float* fc_ws = c_ws + NBH * T_SEQ;
  u16* kbf  = (u16*)((char*)d_ws + gate_bytes);
  u16* vtbf = kbf + kv_elems;

  gate_scan_kernel<<<dim3(NBH), dim3(1024), 0, stream>>>(ig, fg, a_ws, c_ws, fc_ws);
  if (fast) {
    cvt_k_kernel<<<dim3((unsigned)(kv_elems / 1024)), dim3(256), 0, stream>>>(
        k, a_ws, c_ws, kbf);
    cvt_vt_kernel<<<dim3(T_SEQ / 64, NBH), dim3(256), 0, stream>>>(v, vtbf);
    mlstm_fwd_kernel<true><<<dim3(256), dim3(1024), 0, stream>>>(
        q, k, v, kbf, vtbf, a_ws, c_ws, fc_ws, (float*)d_out);
  } else {
    mlstm_fwd_kernel<false><<<dim3(256), dim3(1024), 0, stream>>>(
        q, k, v, kbf, vtbf, a_ws, c_ws, fc_ws, (float*)d_out);
  }
}